// Round 1
// baseline (1043.589 us; speedup 1.0000x reference)
//
#include <hip/hip_runtime.h>
#include <hip/hip_bf16.h>
#include <math.h>

#define NN 512
#define LL 64
#define CCH 32

__device__ __forceinline__ float selu_f(float x) {
    const float sc = 1.0507009873554805f, al = 1.6732632423543772f;
    return x > 0.f ? sc * x : sc * al * expm1f(x);
}

// ---------------- graph construction ----------------

// nv[i][j] = tanh(3*(emb[i,:] . lw[j,:] + lb[j]))
__global__ __launch_bounds__(64) void nodevec_kernel(
    const float* __restrict__ emb, const float* __restrict__ lw,
    const float* __restrict__ lb, float* __restrict__ nv) {
    int i = blockIdx.x, j = threadIdx.x;
    __shared__ float e_s[64];
    e_s[j] = emb[i * 64 + j];
    __syncthreads();
    float acc = lb[j];
    for (int k = 0; k < 64; k++) acc += e_s[k] * lw[j * 64 + k];
    nv[i * 64 + j] = tanhf(3.0f * acc);
}

// adj[v][w] = selu(tanh(3*(nv1[v].nv2[w] - nv2[v].nv1[w])))
__global__ __launch_bounds__(512) void adjacency_kernel(
    const float* __restrict__ nv1, const float* __restrict__ nv2,
    float* __restrict__ adj) {
    int v = blockIdx.x, w = threadIdx.x;
    __shared__ float a1s[64], a2s[64];
    if (threadIdx.x < 64) {
        a1s[threadIdx.x] = nv1[v * 64 + threadIdx.x];
        a2s[threadIdx.x] = nv2[v * 64 + threadIdx.x];
    }
    __syncthreads();
    float acc = 0.f;
    for (int k = 0; k < 64; k++) {
        acc += a1s[k] * nv2[w * 64 + k];
        acc -= a2s[k] * nv1[w * 64 + k];
    }
    adj[v * NN + w] = selu_f(tanhf(3.0f * acc));
}

// per-row top-256 mask (in place) + rowsum(+1)
__global__ __launch_bounds__(256) void topk_kernel(
    float* __restrict__ adj, float* __restrict__ rowsump) {
    __shared__ float orig[512], srt[512];
    __shared__ unsigned char keep[512];
    __shared__ float red[256];
    int v = blockIdx.x, t = threadIdx.x;
    orig[t] = adj[v * NN + t];
    orig[t + 256] = adj[v * NN + t + 256];
    srt[t] = orig[t];
    srt[t + 256] = orig[t + 256];
    __syncthreads();
    // bitonic ascending sort of 512
    for (int k = 2; k <= 512; k <<= 1) {
        for (int j = k >> 1; j > 0; j >>= 1) {
            for (int pass = 0; pass < 2; ++pass) {
                int i = t + pass * 256;
                int ixj = i ^ j;
                if (ixj > i) {
                    bool up = ((i & k) == 0);
                    float a = srt[i], b = srt[ixj];
                    if ((a > b) == up) { srt[i] = b; srt[ixj] = a; }
                }
            }
            __syncthreads();
        }
    }
    float thr = srt[256];  // K-th largest, K=256
    if (t == 0) {
        int g = 0;
        for (int i = 0; i < 512; i++) if (srt[i] > thr) g++;
        int quota = 256 - g;
        for (int w = 0; w < 512; w++) {
            float x = orig[w];
            bool kp = false;
            if (x > thr) kp = true;
            else if (x == thr && quota > 0) { kp = true; quota--; }
            keep[w] = kp ? 1 : 0;
        }
    }
    __syncthreads();
    float part = 0.f;
    for (int pass = 0; pass < 2; pass++) {
        int w = t + pass * 256;
        float val = keep[w] ? orig[w] : 0.0f;
        adj[v * NN + w] = val;
        part += val;
    }
    red[t] = part;
    __syncthreads();
    if (t < 128) red[t] += red[t + 128];
    __syncthreads();
    if (t < 64) {
        float x = red[t] + red[t + 64];
        for (int m = 32; m; m >>= 1) x += __shfl_xor(x, m, 64);
        if (t == 0) rowsump[v] = x + 1.0f;
    }
}

__global__ __launch_bounds__(256) void colsum_kernel(
    const float* __restrict__ adp, float* __restrict__ colsum) {
    int w = blockIdx.x * 256 + threadIdx.x;
    float s = 0.f;
    for (int v = 0; v < NN; v++) s += adp[v * NN + w];
    colsum[w] = s;
}

// a1T[w][v] = (adp[v][w]+d)/rowsump[v]; a2T[w][v] = (adp[w][v]+d)/(colsum[v]+1)
__global__ __launch_bounds__(256) void normalize_kernel(
    const float* __restrict__ adp, const float* __restrict__ rowsump,
    const float* __restrict__ colsum, float* __restrict__ a1T,
    float* __restrict__ a2T) {
    int w = blockIdx.x;
    for (int v = threadIdx.x; v < NN; v += 256) {
        float d = (v == w) ? 1.0f : 0.0f;
        a1T[w * NN + v] = (adp[v * NN + w] + d) / rowsump[v];
        a2T[w * NN + v] = (adp[w * NN + v] + d) / (colsum[v] + 1.0f);
    }
}

// ---------------- main pipeline ----------------

__global__ __launch_bounds__(256) void start_kernel(
    const float* __restrict__ x, const float* __restrict__ sw,
    const float* __restrict__ sb, float* __restrict__ h) {
    int i = blockIdx.x * 256 + threadIdx.x;  // [4][32][512][64]
    int l = i & 63, v = (i >> 6) & 511, c = (i >> 15) & 31, n = i >> 20;
    h[i] = x[(n << 15) + (v << 6) + l] * sw[c] + sb[c];
}

// dst[nc][w][l] = 0.05*base[nc][w][l] + 0.95 * sum_v At[w][v]*src[nc][v][l]
__global__ __launch_bounds__(256) void prop_kernel(
    const float* __restrict__ src, const float* __restrict__ base,
    const float* __restrict__ At, float* __restrict__ dst) {
    __shared__ float h_s[64][64];
    __shared__ float a_s[32][64];
    int nc = blockIdx.x;       // 0..127
    int w0 = blockIdx.y << 5;  // *32
    int t = threadIdx.x;
    int l = t & 63;
    int lh = t & 31;
    int wq = t >> 5;  // 0..7
    float2 acc[4];
#pragma unroll
    for (int j = 0; j < 4; j++) acc[j] = make_float2(0.f, 0.f);
    const float* srcb = src + (size_t)nc * NN * LL;
    for (int v0 = 0; v0 < NN; v0 += 64) {
#pragma unroll
        for (int r = 0; r < 16; r++) {
            int vv = (t >> 6) + 4 * r;
            h_s[vv][l] = srcb[(v0 + vv) * LL + l];
        }
        {
            int vv = t & 63;
#pragma unroll
            for (int r = 0; r < 8; r++) {
                int ww = (t >> 6) + 4 * r;
                a_s[ww][vv] = At[(size_t)(w0 + ww) * NN + v0 + vv];
            }
        }
        __syncthreads();
        for (int vv = 0; vv < 64; vv++) {
            float2 hv = *(const float2*)&h_s[vv][lh * 2];
#pragma unroll
            for (int j = 0; j < 4; j++) {
                float av = a_s[wq + 8 * j][vv];
                acc[j].x += av * hv.x;
                acc[j].y += av * hv.y;
            }
        }
        __syncthreads();
    }
#pragma unroll
    for (int j = 0; j < 4; j++) {
        int w = w0 + wq + 8 * j;
        size_t o = ((size_t)nc * NN + w) * LL + lh * 2;
        float2 bb = *(const float2*)&base[o];
        float2 rr;
        rr.x = 0.05f * bb.x + 0.95f * acc[j].x;
        rr.y = 0.05f * bb.y + 0.95f * acc[j].y;
        *(float2*)&dst[o] = rr;
    }
}

// dst[n][o][v][l] (+)= b[o] + sum_c h0*w[o,c] + h1*w[o,c+32] + h2*w[o,c+64]
template <int ACCUM>
__global__ __launch_bounds__(256) void chanmix_kernel(
    const float* __restrict__ h0, const float* __restrict__ h1,
    const float* __restrict__ h2, const float* __restrict__ w,
    const float* __restrict__ b, float* __restrict__ dst) {
    __shared__ float s0[32][64], s1[32][64], s2[32][64];
    __shared__ float w_s[32 * 96];
    int n = blockIdx.x >> 9, v = blockIdx.x & 511;
    int t = threadIdx.x, l = t & 63, q = t >> 6;
    for (int i = t; i < 32 * 96; i += 256) w_s[i] = w[i];
#pragma unroll
    for (int r = 0; r < 8; r++) {
        int c = q + 4 * r;
        size_t idx = ((size_t)(n * 32 + c) * NN + v) * LL + l;
        s0[c][l] = h0[idx];
        s1[c][l] = h1[idx];
        s2[c][l] = h2[idx];
    }
    __syncthreads();
    float acc[8];
#pragma unroll
    for (int j = 0; j < 8; j++) acc[j] = b[q + 4 * j];
    for (int c = 0; c < 32; c++) {
        float x0 = s0[c][l], x1 = s1[c][l], x2 = s2[c][l];
#pragma unroll
        for (int j = 0; j < 8; j++) {
            int o = q + 4 * j;
            acc[j] += x0 * w_s[o * 96 + c] + x1 * w_s[o * 96 + c + 32] +
                      x2 * w_s[o * 96 + c + 64];
        }
    }
#pragma unroll
    for (int j = 0; j < 8; j++) {
        int o = q + 4 * j;
        size_t idx = ((size_t)(n * 32 + o) * NN + v) * LL + l;
        float r2 = acc[j];
        if (ACCUM) r2 += dst[idx];
        dst[idx] = r2;
    }
}

// LayerNorm over last dim (64), in place. rows = product of leading dims.
__global__ __launch_bounds__(256) void ln_kernel(
    float* __restrict__ h, const float* __restrict__ lw,
    const float* __restrict__ lb) {
    int row = blockIdx.x * 4 + (threadIdx.x >> 6);
    int l = threadIdx.x & 63;
    float x = h[(size_t)row * 64 + l];
    float s = x;
    for (int m = 32; m; m >>= 1) s += __shfl_xor(s, m, 64);
    float u = s * (1.0f / 64.0f);
    float d = x - u;
    float q = d * d;
    for (int m = 32; m; m >>= 1) q += __shfl_xor(q, m, 64);
    float inv = 1.0f / sqrtf(q * (1.0f / 64.0f) + 1e-12f);
    h[(size_t)row * 64 + l] = lw[l] * d * inv + lb[l];
}

// fused: e1 = selu(end1.h); e2 = end2.e1; LN(e2); out[n][l][v] = sum_o e2[o][l]
__global__ __launch_bounds__(256) void end_kernel(
    const float* __restrict__ h, const float* __restrict__ w1,
    const float* __restrict__ b1, const float* __restrict__ w2,
    const float* __restrict__ b2, const float* __restrict__ lw,
    const float* __restrict__ lb, float* __restrict__ out) {
    __shared__ float h_s[32][64];
    __shared__ float e1_s[64][64];
    __shared__ float w1_s[64 * 32];
    __shared__ float w2_s[64 * 64];
    __shared__ float red_s[4][64];
    int n = blockIdx.x >> 9, v = blockIdx.x & 511;
    int t = threadIdx.x, l = t & 63, q = t >> 6;
    for (int i = t; i < 64 * 32; i += 256) w1_s[i] = w1[i];
    for (int i = t; i < 64 * 64; i += 256) w2_s[i] = w2[i];
#pragma unroll
    for (int r = 0; r < 8; r++) {
        int c = q + 4 * r;
        h_s[c][l] = h[((size_t)(n * 32 + c) * NN + v) * LL + l];
    }
    __syncthreads();
    float acc[16];
#pragma unroll
    for (int j = 0; j < 16; j++) acc[j] = b1[q + 4 * j];
    for (int c = 0; c < 32; c++) {
        float x = h_s[c][l];
#pragma unroll
        for (int j = 0; j < 16; j++) acc[j] += x * w1_s[(q + 4 * j) * 32 + c];
    }
#pragma unroll
    for (int j = 0; j < 16; j++) {
        int o = q + 4 * j;
        e1_s[o][l] = selu_f(acc[j]);
    }
    __syncthreads();
    float lwl = lw[l], lbl = lb[l];
    float accw = 0.f;
    for (int r = 0; r < 16; r++) {
        int o = q + 4 * r;
        float val = b2[o];
        for (int c = 0; c < 64; c++) val += e1_s[c][l] * w2_s[o * 64 + c];
        float s = val;
        for (int m = 32; m; m >>= 1) s += __shfl_xor(s, m, 64);
        float u = s * (1.f / 64.f);
        float d = val - u;
        float qq = d * d;
        for (int m = 32; m; m >>= 1) qq += __shfl_xor(qq, m, 64);
        float inv = 1.f / sqrtf(qq * (1.f / 64.f) + 1e-12f);
        accw += lwl * d * inv + lbl;
    }
    red_s[q][l] = accw;
    __syncthreads();
    if (q == 0) {
        float tot = red_s[0][l] + red_s[1][l] + red_s[2][l] + red_s[3][l];
        out[((size_t)n * 64 + l) * NN + v] = tot;
    }
}

// ---------------- launch ----------------

extern "C" void kernel_launch(void* const* d_in, const int* in_sizes, int n_in,
                              void* d_out, int out_size, void* d_ws,
                              size_t ws_size, hipStream_t stream) {
    const float* x = (const float*)d_in[0];
    const float* emb1 = (const float*)d_in[1];
    const float* emb2 = (const float*)d_in[2];
    const float* lin1_w = (const float*)d_in[3];
    const float* lin1_b = (const float*)d_in[4];
    const float* lin2_w = (const float*)d_in[5];
    const float* lin2_b = (const float*)d_in[6];
    const float* start_w = (const float*)d_in[7];
    const float* start_b = (const float*)d_in[8];
    const float* g1_w = (const float*)d_in[9];
    const float* g1_b = (const float*)d_in[10];
    const float* g2_w = (const float*)d_in[11];
    const float* g2_b = (const float*)d_in[12];
    const float* ln_w = (const float*)d_in[13];
    const float* ln_b = (const float*)d_in[14];
    const float* end1_w = (const float*)d_in[15];
    const float* end1_b = (const float*)d_in[16];
    const float* end2_w = (const float*)d_in[17];
    const float* end2_b = (const float*)d_in[18];
    float* out = (float*)d_out;

    char* ws = (char*)d_ws;
    float* nv1 = (float*)(ws + 0);
    float* nv2 = (float*)(ws + 131072);
    float* adp = (float*)(ws + 262144);        // 1 MB, adj then masked in place
    float* a1T = (float*)(ws + 1310720);       // 1 MB
    float* a2T = (float*)(ws + 2359296);       // 1 MB
    float* rowsump = (float*)(ws + 3407872);   // 2 KB
    float* colsum = (float*)(ws + 3409920);    // 2 KB
    float* hA = (float*)(ws + 4194304);        // 16 MB
    float* hB = (float*)(ws + 20971520);       // 16 MB
    float* p1 = (float*)(ws + 37748736);       // 16 MB
    float* p2 = (float*)(ws + 54525952);       // 16 MB (ends at 68 MB)

    // graph construction
    nodevec_kernel<<<512, 64, 0, stream>>>(emb1, lin1_w, lin1_b, nv1);
    nodevec_kernel<<<512, 64, 0, stream>>>(emb2, lin2_w, lin2_b, nv2);
    adjacency_kernel<<<512, 512, 0, stream>>>(nv1, nv2, adp);
    topk_kernel<<<512, 256, 0, stream>>>(adp, rowsump);
    colsum_kernel<<<2, 256, 0, stream>>>(adp, colsum);
    normalize_kernel<<<512, 256, 0, stream>>>(adp, rowsump, colsum, a1T, a2T);

    // start conv
    start_kernel<<<16384, 256, 0, stream>>>(x, start_w, start_b, hA);

    dim3 pgrid(128, 16);
    float* cur = hA;
    float* nxt = hB;
    for (int layer = 0; layer < 2; layer++) {
        const float* w1 = g1_w + layer * 32 * 96;
        const float* bb1 = g1_b + layer * 32;
        const float* w2 = g2_w + layer * 32 * 96;
        const float* bb2 = g2_b + layer * 32;
        prop_kernel<<<pgrid, 256, 0, stream>>>(cur, cur, a1T, p1);
        prop_kernel<<<pgrid, 256, 0, stream>>>(p1, cur, a1T, p2);
        chanmix_kernel<0><<<2048, 256, 0, stream>>>(cur, p1, p2, w1, bb1, nxt);
        prop_kernel<<<pgrid, 256, 0, stream>>>(cur, cur, a2T, p1);
        prop_kernel<<<pgrid, 256, 0, stream>>>(p1, cur, a2T, p2);
        chanmix_kernel<1><<<2048, 256, 0, stream>>>(cur, p1, p2, w2, bb2, nxt);
        float* tmp = cur;
        cur = nxt;
        nxt = tmp;
    }
    // after 2 layers result is back in hA (== cur)

    // layernorm over L on [4*32*512] rows
    ln_kernel<<<16384, 256, 0, stream>>>(cur, ln_w, ln_b);

    // fused end1+selu+end2+LN+sum-over-channels
    end_kernel<<<2048, 256, 0, stream>>>(cur, end1_w, end1_b, end2_w, end2_b,
                                         ln_w, ln_b, out);
}

// Round 4
// 582.217 us; speedup vs baseline: 1.7924x; 1.7924x over previous
//
#include <hip/hip_runtime.h>
#include <hip/hip_bf16.h>
#include <math.h>

#define NN 512

typedef __attribute__((ext_vector_type(8))) short short8;
typedef __attribute__((ext_vector_type(4))) float f32x4;

__device__ __forceinline__ float selu_f(float x) {
    const float sc = 1.0507009873554805f, al = 1.6732632423543772f;
    return x > 0.f ? sc * x : sc * al * expm1f(x);
}
__device__ __forceinline__ unsigned short f2b(float f) {
    unsigned int u = __float_as_uint(f);
    unsigned int r = (u + 0x7fffu + ((u >> 16) & 1u)) >> 16;
    return (unsigned short)r;
}
__device__ __forceinline__ float b2f(unsigned short h) {
    return __uint_as_float(((unsigned int)h) << 16);
}
__device__ __forceinline__ float ulo(unsigned int u) {
    return __uint_as_float(u << 16);
}
__device__ __forceinline__ float uhi(unsigned int u) {
    return __uint_as_float(u & 0xffff0000u);
}
__device__ __forceinline__ unsigned int pk2(float a, float b) {
    return (unsigned int)f2b(a) | ((unsigned int)f2b(b) << 16);
}
__device__ __forceinline__ void gload16(const void* g, void* l) {
    __builtin_amdgcn_global_load_lds(
        (const __attribute__((address_space(1))) unsigned int*)g,
        (__attribute__((address_space(3))) unsigned int*)l, 16, 0, 0);
}

// ---------------- graph construction (f32) ----------------

__global__ __launch_bounds__(64) void nodevec_kernel(
    const float* __restrict__ emb, const float* __restrict__ lw,
    const float* __restrict__ lb, float* __restrict__ nv) {
    int i = blockIdx.x, j = threadIdx.x;
    __shared__ float e_s[64];
    e_s[j] = emb[i * 64 + j];
    __syncthreads();
    float acc = lb[j];
    for (int k = 0; k < 64; k++) acc += e_s[k] * lw[j * 64 + k];
    nv[i * 64 + j] = tanhf(3.0f * acc);
}

__global__ __launch_bounds__(512) void adjacency_kernel(
    const float* __restrict__ nv1, const float* __restrict__ nv2,
    float* __restrict__ adj) {
    int v = blockIdx.x, w = threadIdx.x;
    __shared__ float a1s[64], a2s[64];
    if (threadIdx.x < 64) {
        a1s[threadIdx.x] = nv1[v * 64 + threadIdx.x];
        a2s[threadIdx.x] = nv2[v * 64 + threadIdx.x];
    }
    __syncthreads();
    float acc = 0.f;
    for (int k = 0; k < 64; k++) {
        acc += a1s[k] * nv2[w * 64 + k];
        acc -= a2s[k] * nv1[w * 64 + k];
    }
    adj[v * NN + w] = selu_f(tanhf(3.0f * acc));
}

__global__ __launch_bounds__(256) void topk_kernel(
    float* __restrict__ adj, float* __restrict__ rowsump) {
    __shared__ float orig[512], srt[512];
    __shared__ unsigned char keep[512];
    __shared__ float red[256];
    int v = blockIdx.x, t = threadIdx.x;
    orig[t] = adj[v * NN + t];
    orig[t + 256] = adj[v * NN + t + 256];
    srt[t] = orig[t];
    srt[t + 256] = orig[t + 256];
    __syncthreads();
    for (int k = 2; k <= 512; k <<= 1) {
        for (int j = k >> 1; j > 0; j >>= 1) {
            for (int pass = 0; pass < 2; ++pass) {
                int i = t + pass * 256;
                int ixj = i ^ j;
                if (ixj > i) {
                    bool up = ((i & k) == 0);
                    float a = srt[i], b = srt[ixj];
                    if ((a > b) == up) { srt[i] = b; srt[ixj] = a; }
                }
            }
            __syncthreads();
        }
    }
    float thr = srt[256];
    if (t == 0) {
        int g = 0;
        for (int i = 0; i < 512; i++) if (srt[i] > thr) g++;
        int quota = 256 - g;
        for (int w = 0; w < 512; w++) {
            float x = orig[w];
            bool kp = false;
            if (x > thr) kp = true;
            else if (x == thr && quota > 0) { kp = true; quota--; }
            keep[w] = kp ? 1 : 0;
        }
    }
    __syncthreads();
    float part = 0.f;
    for (int pass = 0; pass < 2; pass++) {
        int w = t + pass * 256;
        float val = keep[w] ? orig[w] : 0.0f;
        adj[v * NN + w] = val;
        part += val;
    }
    red[t] = part;
    __syncthreads();
    if (t < 128) red[t] += red[t + 128];
    __syncthreads();
    if (t < 64) {
        float x = red[t] + red[t + 64];
        for (int m = 32; m; m >>= 1) x += __shfl_xor(x, m, 64);
        if (t == 0) rowsump[v] = x + 1.0f;
    }
}

__global__ __launch_bounds__(256) void colsum_kernel(
    const float* __restrict__ adp, float* __restrict__ colsum) {
    int w = blockIdx.x * 256 + threadIdx.x;
    float s = 0.f;
    for (int v = 0; v < NN; v++) s += adp[v * NN + w];
    colsum[w] = s;
}

// adjacency stored hi/lo split: aT[w][0..511]=hi, aT[w][512..1023]=lo
__global__ __launch_bounds__(256) void normalize_kernel(
    const float* __restrict__ adp, const float* __restrict__ rowsump,
    const float* __restrict__ colsum, unsigned short* __restrict__ a1T,
    unsigned short* __restrict__ a2T) {
    int w = blockIdx.x;
    for (int v = threadIdx.x; v < NN; v += 256) {
        float d = (v == w) ? 1.0f : 0.0f;
        float f1 = (adp[v * NN + w] + d) / rowsump[v];
        float f2 = (adp[w * NN + v] + d) / (colsum[v] + 1.0f);
        unsigned short h1 = f2b(f1), h2 = f2b(f2);
        a1T[w * 1024 + v] = h1;
        a1T[w * 1024 + 512 + v] = f2b(f1 - b2f(h1));
        a2T[w * 1024 + v] = h2;
        a2T[w * 1024 + 512 + v] = f2b(f2 - b2f(h2));
    }
}

// ---------------- main pipeline ----------------
// h storage: [j=(n,c,l)][1024] bf16; cols 0..511 = hi, 512..1023 = lo.
// value(j,v) = hi + lo  (f32-accurate to 2^-18)

__global__ __launch_bounds__(256) void start_kernel(
    const float* __restrict__ x, const float* __restrict__ sw,
    const float* __restrict__ sb, unsigned int* __restrict__ h_u) {
    int n = blockIdx.x >> 6, l = blockIdx.x & 63;
    int t = threadIdx.x;
    float x0 = x[(n * 512 + 2 * t) * 64 + l];
    float x1 = x[(n * 512 + 2 * t + 1) * 64 + l];
#pragma unroll
    for (int c = 0; c < 32; c++) {
        float wc = sw[c], bc = sb[c];
        float f0 = x0 * wc + bc;
        float f1 = x1 * wc + bc;
        unsigned short h0 = f2b(f0), h1 = f2b(f1);
        float l0 = f0 - b2f(h0), l1 = f1 - b2f(h1);
        int j = (n * 32 + c) * 64 + l;
        h_u[j * 512 + t] = (unsigned int)h0 | ((unsigned int)h1 << 16);
        h_u[j * 512 + 256 + t] = pk2(l0, l1);
    }
}

// dst(j,w) = 0.05*base(j,w) + 0.95 * sum_v value(j,v)*a[v][w]
// Compensated K=1536 GEMM: A''=[h_hi|h_lo|h_hi], B''=[a_hi;a_hi;a_lo].
// BM=128 BN=64 BK=32, grid(64,8), 256 thr.
__global__ __launch_bounds__(256) void prop_mfma(
    const unsigned short* __restrict__ H, const unsigned short* __restrict__ base,
    const unsigned short* __restrict__ AT, unsigned short* __restrict__ dst) {
    __shared__ __align__(16) short At[128 * 32];  // 8 KB
    __shared__ __align__(16) short Bt[64 * 32];   // 4 KB
    int t = threadIdx.x;
    int lane = t & 63;
    int wid = t >> 6;
    int wm = wid >> 1, wn = wid & 1;
    int j0 = blockIdx.x << 7;
    int w0 = blockIdx.y << 6;
    f32x4 acc[4][2];
#pragma unroll
    for (int m = 0; m < 4; m++)
#pragma unroll
        for (int n = 0; n < 2; n++) acc[m][n] = (f32x4)0.f;

    int l15 = lane & 15;
    int lhi = lane >> 4;
    for (int kk = 0; kk < 1536; kk += 32) {
        int ca = (kk < 1024) ? kk : (kk - 1024);  // h col: hi, lo, hi
        int cb = (kk < 512) ? kk : (kk - 512);    // a col: hi, hi, lo
#pragma unroll
        for (int it = 0; it < 2; it++) {
            int slot = it * 256 + t;
            int r = slot >> 2, ch = slot & 3;
            gload16(H + (j0 + r) * 1024 + ca + (ch << 3), At + slot * 8);
        }
        {
            int r = t >> 2, ch = t & 3;
            gload16(AT + (w0 + r) * 1024 + cb + (ch << 3), Bt + t * 8);
        }
        __syncthreads();
        short8 a[4], b[2];
#pragma unroll
        for (int m = 0; m < 4; m++)
            a[m] = *(const short8*)&At[(wm * 64 + m * 16 + l15) * 32 + lhi * 8];
#pragma unroll
        for (int n = 0; n < 2; n++)
            b[n] = *(const short8*)&Bt[(wn * 32 + n * 16 + l15) * 32 + lhi * 8];
#pragma unroll
        for (int m = 0; m < 4; m++)
#pragma unroll
            for (int n = 0; n < 2; n++)
                acc[m][n] = __builtin_amdgcn_mfma_f32_16x16x32_bf16(
                    a[m], b[n], acc[m][n], 0, 0, 0);
        __syncthreads();
    }
    // C/D: col = lane&15, row = (lane>>4)*4 + reg
#pragma unroll
    for (int m = 0; m < 4; m++) {
#pragma unroll
        for (int n = 0; n < 2; n++) {
#pragma unroll
            for (int r = 0; r < 4; r++) {
                int row = j0 + wm * 64 + m * 16 + lhi * 4 + r;
                int col = w0 + wn * 32 + n * 16 + l15;
                int ih = row * 1024 + col;
                float bf = b2f(base[ih]) + b2f(base[ih + 512]);
                float f = 0.05f * bf + 0.95f * acc[m][n][r];
                unsigned short hi = f2b(f);
                dst[ih] = hi;
                dst[ih + 512] = f2b(f - b2f(hi));
            }
        }
    }
}

// dst[n][o][l][v] (+)= b[o] + sum_c h0*W[o,c] + h1*W[o,c+32] + h2*W[o,c+64]
template <int ACCUM>
__global__ __launch_bounds__(256) void chanmix_kernel(
    const unsigned int* __restrict__ h0, const unsigned int* __restrict__ h1,
    const unsigned int* __restrict__ h2, const float* __restrict__ w,
    const float* __restrict__ b, unsigned int* __restrict__ dst_u) {
    __shared__ float ws[32 * 96];
    int bid = blockIdx.x;
    int vc = bid & 3, l = (bid >> 2) & 63, n = bid >> 8;
    int t = threadIdx.x;
    int vl = t & 63, q = t >> 6;
    for (int i = t; i < 32 * 96; i += 256) ws[i] = w[i];
    __syncthreads();
    float acc[8][2];
#pragma unroll
    for (int oo = 0; oo < 8; oo++) {
        float bb = b[q * 8 + oo];
        acc[oo][0] = bb;
        acc[oo][1] = bb;
    }
    int uoff = vc * 64 + vl;
    for (int c = 0; c < 32; c++) {
        int j = (n * 32 + c) * 64 + l;
        unsigned int h0h = h0[j * 512 + uoff], h0l = h0[j * 512 + 256 + uoff];
        unsigned int h1h = h1[j * 512 + uoff], h1l = h1[j * 512 + 256 + uoff];
        unsigned int h2h = h2[j * 512 + uoff], h2l = h2[j * 512 + 256 + uoff];
        float x0l = ulo(h0h) + ulo(h0l), x0h = uhi(h0h) + uhi(h0l);
        float x1l = ulo(h1h) + ulo(h1l), x1h = uhi(h1h) + uhi(h1l);
        float x2l = ulo(h2h) + ulo(h2l), x2h = uhi(h2h) + uhi(h2l);
#pragma unroll
        for (int oo = 0; oo < 8; oo++) {
            int o = q * 8 + oo;
            float w0c = ws[o * 96 + c];
            float w1c = ws[o * 96 + 32 + c];
            float w2c = ws[o * 96 + 64 + c];
            acc[oo][0] += x0l * w0c + x1l * w1c + x2l * w2c;
            acc[oo][1] += x0h * w0c + x1h * w1c + x2h * w2c;
        }
    }
#pragma unroll
    for (int oo = 0; oo < 8; oo++) {
        int o = q * 8 + oo;
        int j = (n * 32 + o) * 64 + l;
        float a0 = acc[oo][0], a1 = acc[oo][1];
        if (ACCUM) {
            unsigned int oh = dst_u[j * 512 + uoff];
            unsigned int ol = dst_u[j * 512 + 256 + uoff];
            a0 += ulo(oh) + ulo(ol);
            a1 += uhi(oh) + uhi(ol);
        }
        unsigned short hi0 = f2b(a0), hi1 = f2b(a1);
        float lo0 = a0 - b2f(hi0), lo1 = a1 - b2f(hi1);
        dst_u[j * 512 + uoff] = (unsigned int)hi0 | ((unsigned int)hi1 << 16);
        dst_u[j * 512 + 256 + uoff] = pk2(lo0, lo1);
    }
}

// LayerNorm over l. grid = n*c = 128, 256 thr (one v-pair each).
__global__ __launch_bounds__(256) void ln_kernel(
    unsigned int* __restrict__ h_u, const float* __restrict__ lw,
    const float* __restrict__ lb) {
    int nc = blockIdx.x;
    int t = threadIdx.x;
    unsigned int base = nc * 32768 + t;
    float s0 = 0.f, s1 = 0.f, q0 = 0.f, q1 = 0.f;
    for (int l = 0; l < 64; l++) {
        unsigned int hi = h_u[base + l * 512];
        unsigned int lo = h_u[base + l * 512 + 256];
        float f0 = ulo(hi) + ulo(lo), f1 = uhi(hi) + uhi(lo);
        s0 += f0; s1 += f1;
        q0 += f0 * f0; q1 += f1 * f1;
    }
    float m0 = s0 * (1.f / 64.f), m1 = s1 * (1.f / 64.f);
    float v0 = fmaxf(q0 * (1.f / 64.f) - m0 * m0, 0.f);
    float v1 = fmaxf(q1 * (1.f / 64.f) - m1 * m1, 0.f);
    float i0 = 1.f / sqrtf(v0 + 1e-12f);
    float i1 = 1.f / sqrtf(v1 + 1e-12f);
    for (int l = 0; l < 64; l++) {
        unsigned int hi = h_u[base + l * 512];
        unsigned int lo = h_u[base + l * 512 + 256];
        float wl = lw[l], bl = lb[l];
        float f0 = wl * (ulo(hi) + ulo(lo) - m0) * i0 + bl;
        float f1 = wl * (uhi(hi) + uhi(lo) - m1) * i1 + bl;
        unsigned short p0 = f2b(f0), p1 = f2b(f1);
        h_u[base + l * 512] = (unsigned int)p0 | ((unsigned int)p1 << 16);
        h_u[base + l * 512 + 256] = pk2(f0 - b2f(p0), f1 - b2f(p1));
    }
}

// fused end1+selu+end2+LN+sum-over-o2. grid (n, vblk4) = 512 blocks.
__global__ __launch_bounds__(256) void end_kernel(
    const unsigned short* __restrict__ h, const float* __restrict__ w1,
    const float* __restrict__ b1, const float* __restrict__ w2,
    const float* __restrict__ b2, const float* __restrict__ lw,
    const float* __restrict__ lb, float* __restrict__ out) {
    __shared__ __align__(16) float hs[32 * 64 * 4];     // 32 KB
    __shared__ float w1T[32 * 64];                      // 8 KB
    __shared__ float w2T[64 * 64];                      // 16 KB
    __shared__ __align__(16) unsigned short e1s[4 * 4128];  // 33 KB
    __shared__ float red[4 * 64 * 4];                   // 4 KB
    int n = blockIdx.x >> 7, vb = blockIdx.x & 127;
    int vbase = vb * 4;
    int t = threadIdx.x;
    for (int i = t; i < 2048; i += 256) {
        int o1 = i >> 5, c = i & 31;
        w1T[c * 64 + o1] = w1[i];
    }
    for (int i = t; i < 4096; i += 256) {
        int o2 = i >> 6, o1 = i & 63;
        w2T[o1 * 64 + o2] = w2[i];
    }
#pragma unroll
    for (int k = 0; k < 8; k++) {
        int s2 = t + k * 256;
        int c = s2 >> 6, l = s2 & 63;
        const unsigned short* p = h + ((size_t)((n * 32 + c) * 64 + l) << 10) + vbase;
        uint2 hiv = *(const uint2*)p;
        uint2 lov = *(const uint2*)(p + 512);
        hs[s2 * 4 + 0] = ulo(hiv.x) + ulo(lov.x);
        hs[s2 * 4 + 1] = uhi(hiv.x) + uhi(lov.x);
        hs[s2 * 4 + 2] = ulo(hiv.y) + ulo(lov.y);
        hs[s2 * 4 + 3] = uhi(hiv.y) + uhi(lov.y);
    }
    __syncthreads();
    // phase B: e1[o1][l][vq] = selu(b1 + sum_c h*w1)
    {
        int lq = t & 63, og = t >> 6;
        float acc[16][4];
#pragma unroll
        for (int oo = 0; oo < 16; oo++) {
            float bb = b1[og * 16 + oo];
#pragma unroll
            for (int vq = 0; vq < 4; vq++) acc[oo][vq] = bb;
        }
        for (int c = 0; c < 32; c++) {
            float4 hv = *(const float4*)&hs[(c * 64 + lq) * 4];
#pragma unroll
            for (int oo = 0; oo < 16; oo++) {
                float wc = w1T[c * 64 + og * 16 + oo];
                acc[oo][0] += hv.x * wc;
                acc[oo][1] += hv.y * wc;
                acc[oo][2] += hv.z * wc;
                acc[oo][3] += hv.w * wc;
            }
        }
#pragma unroll
        for (int oo = 0; oo < 16; oo++) {
            int o = og * 16 + oo;
#pragma unroll
            for (int vq = 0; vq < 4; vq++)
                e1s[vq * 4128 + o * 64 + lq] = f2b(selu_f(acc[oo][vq]));
        }
    }
    __syncthreads();
    // phase C: e2 row per (o2,vq), LN over l, reduce over o2
    {
        int o2 = t >> 2, vq = t & 3;
        float e2r[64];
        float bb = b2[o2];
#pragma unroll
        for (int l = 0; l < 64; l++) e2r[l] = bb;
        for (int o1 = 0; o1 < 64; o1++) {
            float wv = w2T[o1 * 64 + o2];
            const unsigned int* ep = (const unsigned int*)&e1s[vq * 4128 + o1 * 64];
#pragma unroll
            for (int lb8 = 0; lb8 < 8; lb8++) {
                uint4 pk = *(const uint4*)&ep[lb8 * 4];
                e2r[lb8 * 8 + 0] += ulo(pk.x) * wv;
                e2r[lb8 * 8 + 1] += uhi(pk.x) * wv;
                e2r[lb8 * 8 + 2] += ulo(pk.y) * wv;
                e2r[lb8 * 8 + 3] += uhi(pk.y) * wv;
                e2r[lb8 * 8 + 4] += ulo(pk.z) * wv;
                e2r[lb8 * 8 + 5] += uhi(pk.z) * wv;
                e2r[lb8 * 8 + 6] += ulo(pk.w) * wv;
                e2r[lb8 * 8 + 7] += uhi(pk.w) * wv;
            }
        }
        float s = 0.f;
#pragma unroll
        for (int l = 0; l < 64; l++) s += e2r[l];
        float u = s * (1.f / 64.f);
        float qq = 0.f;
#pragma unroll
        for (int l = 0; l < 64; l++) {
            float d = e2r[l] - u;
            qq += d * d;
        }
        float inv = 1.f / sqrtf(qq * (1.f / 64.f) + 1e-12f);
        int wid = t >> 6;
#pragma unroll
        for (int l = 0; l < 64; l++) {
            float nrm = lw[l] * (e2r[l] - u) * inv + lb[l];
            nrm += __shfl_xor(nrm, 4, 64);
            nrm += __shfl_xor(nrm, 8, 64);
            nrm += __shfl_xor(nrm, 16, 64);
            nrm += __shfl_xor(nrm, 32, 64);
            if ((t & 63) < 4) red[(wid * 64 + l) * 4 + vq] = nrm;
        }
    }
    __syncthreads();
    {
        int l = t >> 2, vq = t & 3;
        float tot = red[(0 * 64 + l) * 4 + vq] + red[(1 * 64 + l) * 4 + vq] +
                    red[(2 * 64 + l) * 4 + vq] + red[(3 * 64 + l) * 4 + vq];
        out[(n * 64 + l) * 512 + vbase + vq] = tot;
    }
}

// ---------------- launch ----------------

extern "C" void kernel_launch(void* const* d_in, const int* in_sizes, int n_in,
                              void* d_out, int out_size, void* d_ws,
                              size_t ws_size, hipStream_t stream) {
    const float* x = (const float*)d_in[0];
    const float* emb1 = (const float*)d_in[1];
    const float* emb2 = (const float*)d_in[2];
    const float* lin1_w = (const float*)d_in[3];
    const float* lin1_b = (const float*)d_in[4];
    const float* lin2_w = (const float*)d_in[5];
    const float* lin2_b = (const float*)d_in[6];
    const float* start_w = (const float*)d_in[7];
    const float* start_b = (const float*)d_in[8];
    const float* g1_w = (const float*)d_in[9];
    const float* g1_b = (const float*)d_in[10];
    const float* g2_w = (const float*)d_in[11];
    const float* g2_b = (const float*)d_in[12];
    const float* ln_w = (const float*)d_in[13];
    const float* ln_b = (const float*)d_in[14];
    const float* end1_w = (const float*)d_in[15];
    const float* end1_b = (const float*)d_in[16];
    const float* end2_w = (const float*)d_in[17];
    const float* end2_b = (const float*)d_in[18];
    float* out = (float*)d_out;

    char* ws = (char*)d_ws;
    float* nv1 = (float*)(ws + 0);
    float* nv2 = (float*)(ws + 131072);
    float* adp = (float*)(ws + 262144);                     // 1 MB f32
    unsigned short* a1T = (unsigned short*)(ws + 1310720);  // 1 MB hi/lo
    unsigned short* a2T = (unsigned short*)(ws + 2359296);  // 1 MB hi/lo
    float* rowsump = (float*)(ws + 3407872);
    float* colsum = (float*)(ws + 3409920);
    unsigned short* hA = (unsigned short*)(ws + 4194304);   // 16 MB split
    unsigned short* hB = (unsigned short*)(ws + 20971520);  // 16 MB
    unsigned short* p1 = (unsigned short*)(ws + 37748736);  // 16 MB
    unsigned short* p2 = (unsigned short*)(ws + 54525952);  // 16 MB (ends 68MB)

    nodevec_kernel<<<512, 64, 0, stream>>>(emb1, lin1_w, lin1_b, nv1);
    nodevec_kernel<<<512, 64, 0, stream>>>(emb2, lin2_w, lin2_b, nv2);
    adjacency_kernel<<<512, 512, 0, stream>>>(nv1, nv2, adp);
    topk_kernel<<<512, 256, 0, stream>>>(adp, rowsump);
    colsum_kernel<<<2, 256, 0, stream>>>(adp, colsum);
    normalize_kernel<<<512, 256, 0, stream>>>(adp, rowsump, colsum, a1T, a2T);

    start_kernel<<<256, 256, 0, stream>>>(x, start_w, start_b, (unsigned int*)hA);

    dim3 pgrid(64, 8);
    unsigned short* cur = hA;
    unsigned short* nxt = hB;
    for (int layer = 0; layer < 2; layer++) {
        const float* w1 = g1_w + layer * 32 * 96;
        const float* bb1 = g1_b + layer * 32;
        const float* w2 = g2_w + layer * 32 * 96;
        const float* bb2 = g2_b + layer * 32;
        prop_mfma<<<pgrid, 256, 0, stream>>>(cur, cur, a1T, p1);
        prop_mfma<<<pgrid, 256, 0, stream>>>(p1, cur, a1T, p2);
        chanmix_kernel<0><<<1024, 256, 0, stream>>>(
            (const unsigned int*)cur, (const unsigned int*)p1,
            (const unsigned int*)p2, w1, bb1, (unsigned int*)nxt);
        prop_mfma<<<pgrid, 256, 0, stream>>>(cur, cur, a2T, p1);
        prop_mfma<<<pgrid, 256, 0, stream>>>(p1, cur, a2T, p2);
        chanmix_kernel<1><<<1024, 256, 0, stream>>>(
            (const unsigned int*)cur, (const unsigned int*)p1,
            (const unsigned int*)p2, w2, bb2, (unsigned int*)nxt);
        unsigned short* tmp = cur;
        cur = nxt;
        nxt = tmp;
    }

    ln_kernel<<<128, 256, 0, stream>>>((unsigned int*)cur, ln_w, ln_b);
    end_kernel<<<512, 256, 0, stream>>>(cur, end1_w, end1_b, end2_w, end2_b,
                                        ln_w, ln_b, out);
}

// Round 5
// 512.592 us; speedup vs baseline: 2.0359x; 1.1358x over previous
//
#include <hip/hip_runtime.h>
#include <hip/hip_bf16.h>
#include <math.h>

#define NN 512

typedef __attribute__((ext_vector_type(8))) short short8;
typedef __attribute__((ext_vector_type(4))) float f32x4;

__device__ __forceinline__ float selu_f(float x) {
    const float sc = 1.0507009873554805f, al = 1.6732632423543772f;
    return x > 0.f ? sc * x : sc * al * expm1f(x);
}
__device__ __forceinline__ unsigned short f2b(float f) {
    unsigned int u = __float_as_uint(f);
    unsigned int r = (u + 0x7fffu + ((u >> 16) & 1u)) >> 16;
    return (unsigned short)r;
}
__device__ __forceinline__ float b2f(unsigned short h) {
    return __uint_as_float(((unsigned int)h) << 16);
}
__device__ __forceinline__ float ulo(unsigned int u) {
    return __uint_as_float(u << 16);
}
__device__ __forceinline__ float uhi(unsigned int u) {
    return __uint_as_float(u & 0xffff0000u);
}
__device__ __forceinline__ unsigned int pk2(float a, float b) {
    return (unsigned int)f2b(a) | ((unsigned int)f2b(b) << 16);
}
__device__ __forceinline__ void gload16(const void* g, void* l) {
    __builtin_amdgcn_global_load_lds(
        (const __attribute__((address_space(1))) unsigned int*)g,
        (__attribute__((address_space(3))) unsigned int*)l, 16, 0, 0);
}
__device__ __forceinline__ float wred(float x) {
    x += __shfl_xor(x, 1, 64);
    x += __shfl_xor(x, 2, 64);
    x += __shfl_xor(x, 4, 64);
    x += __shfl_xor(x, 8, 64);
    x += __shfl_xor(x, 16, 64);
    x += __shfl_xor(x, 32, 64);
    return x;
}

// ---------------- graph construction (f32) ----------------

__global__ __launch_bounds__(64) void nodevec_kernel(
    const float* __restrict__ emb, const float* __restrict__ lw,
    const float* __restrict__ lb, float* __restrict__ nv) {
    int i = blockIdx.x, j = threadIdx.x;
    __shared__ float e_s[64];
    e_s[j] = emb[i * 64 + j];
    __syncthreads();
    float acc = lb[j];
    for (int k = 0; k < 64; k++) acc += e_s[k] * lw[j * 64 + k];
    nv[i * 64 + j] = tanhf(3.0f * acc);
}

__global__ __launch_bounds__(512) void adjacency_kernel(
    const float* __restrict__ nv1, const float* __restrict__ nv2,
    float* __restrict__ adj) {
    int v = blockIdx.x, w = threadIdx.x;
    __shared__ float a1s[64], a2s[64];
    if (threadIdx.x < 64) {
        a1s[threadIdx.x] = nv1[v * 64 + threadIdx.x];
        a2s[threadIdx.x] = nv2[v * 64 + threadIdx.x];
    }
    __syncthreads();
    float acc = 0.f;
    for (int k = 0; k < 64; k++) {
        acc += a1s[k] * nv2[w * 64 + k];
        acc -= a2s[k] * nv1[w * 64 + k];
    }
    adj[v * NN + w] = selu_f(tanhf(3.0f * acc));
}

__global__ __launch_bounds__(256) void topk_kernel(
    float* __restrict__ adj, float* __restrict__ rowsump) {
    __shared__ float orig[512], srt[512];
    __shared__ unsigned char keep[512];
    __shared__ float red[256];
    int v = blockIdx.x, t = threadIdx.x;
    orig[t] = adj[v * NN + t];
    orig[t + 256] = adj[v * NN + t + 256];
    srt[t] = orig[t];
    srt[t + 256] = orig[t + 256];
    __syncthreads();
    for (int k = 2; k <= 512; k <<= 1) {
        for (int j = k >> 1; j > 0; j >>= 1) {
            for (int pass = 0; pass < 2; ++pass) {
                int i = t + pass * 256;
                int ixj = i ^ j;
                if (ixj > i) {
                    bool up = ((i & k) == 0);
                    float a = srt[i], b = srt[ixj];
                    if ((a > b) == up) { srt[i] = b; srt[ixj] = a; }
                }
            }
            __syncthreads();
        }
    }
    float thr = srt[256];
    if (t == 0) {
        int g = 0;
        for (int i = 0; i < 512; i++) if (srt[i] > thr) g++;
        int quota = 256 - g;
        for (int w = 0; w < 512; w++) {
            float x = orig[w];
            bool kp = false;
            if (x > thr) kp = true;
            else if (x == thr && quota > 0) { kp = true; quota--; }
            keep[w] = kp ? 1 : 0;
        }
    }
    __syncthreads();
    float part = 0.f;
    for (int pass = 0; pass < 2; pass++) {
        int w = t + pass * 256;
        float val = keep[w] ? orig[w] : 0.0f;
        adj[v * NN + w] = val;
        part += val;
    }
    red[t] = part;
    __syncthreads();
    if (t < 128) red[t] += red[t + 128];
    __syncthreads();
    if (t < 64) {
        float x = red[t] + red[t + 64];
        for (int m = 32; m; m >>= 1) x += __shfl_xor(x, m, 64);
        if (t == 0) rowsump[v] = x + 1.0f;
    }
}

__global__ __launch_bounds__(256) void colsum_kernel(
    const float* __restrict__ adp, float* __restrict__ colsum) {
    int w = blockIdx.x * 256 + threadIdx.x;
    float s = 0.f;
    for (int v = 0; v < NN; v++) s += adp[v * NN + w];
    colsum[w] = s;
}

// adjacency stored hi/lo split: aT[w][0..511]=hi, aT[w][512..1023]=lo
__global__ __launch_bounds__(256) void normalize_kernel(
    const float* __restrict__ adp, const float* __restrict__ rowsump,
    const float* __restrict__ colsum, unsigned short* __restrict__ a1T,
    unsigned short* __restrict__ a2T) {
    int w = blockIdx.x;
    for (int v = threadIdx.x; v < NN; v += 256) {
        float d = (v == w) ? 1.0f : 0.0f;
        float f1 = (adp[v * NN + w] + d) / rowsump[v];
        float f2 = (adp[w * NN + v] + d) / (colsum[v] + 1.0f);
        unsigned short h1 = f2b(f1), h2 = f2b(f2);
        a1T[w * 1024 + v] = h1;
        a1T[w * 1024 + 512 + v] = f2b(f1 - b2f(h1));
        a2T[w * 1024 + v] = h2;
        a2T[w * 1024 + 512 + v] = f2b(f2 - b2f(h2));
    }
}

// ---------------- main pipeline ----------------
// h storage: [j=(n,c,l)][1024] bf16; cols 0..511 = hi, 512..1023 = lo.

__global__ __launch_bounds__(256) void start_kernel(
    const float* __restrict__ x, const float* __restrict__ sw,
    const float* __restrict__ sb, unsigned int* __restrict__ h_u) {
    int n = blockIdx.x >> 6, l = blockIdx.x & 63;
    int t = threadIdx.x;
    float x0 = x[(n * 512 + 2 * t) * 64 + l];
    float x1 = x[(n * 512 + 2 * t + 1) * 64 + l];
#pragma unroll
    for (int c = 0; c < 32; c++) {
        float wc = sw[c], bc = sb[c];
        float f0 = x0 * wc + bc;
        float f1 = x1 * wc + bc;
        unsigned short h0 = f2b(f0), h1 = f2b(f1);
        float l0 = f0 - b2f(h0), l1 = f1 - b2f(h1);
        int j = (n * 32 + c) * 64 + l;
        h_u[j * 512 + t] = (unsigned int)h0 | ((unsigned int)h1 << 16);
        h_u[j * 512 + 256 + t] = pk2(l0, l1);
    }
}

// dst(j,w) = 0.05*base(j,w) + 0.95 * sum_v value(j,v)*a[v][w]
// Compensated K=1536: A''=[h_hi|h_lo|h_hi], B''=[a_hi;a_hi;a_lo].
// BM=128 BN=64 BK=64, grid(64,8), 256 thr. XOR-swizzled LDS (src-preswizzle).
__global__ __launch_bounds__(256) void prop_mfma(
    const unsigned short* __restrict__ H, const unsigned short* __restrict__ base,
    const unsigned short* __restrict__ AT, unsigned short* __restrict__ dst) {
    __shared__ __align__(16) short At[128 * 64];  // 16 KB
    __shared__ __align__(16) short Bt[64 * 64];   // 8 KB
    int t = threadIdx.x;
    int lane = t & 63;
    int wid = t >> 6;
    int wm = wid >> 1, wn = wid & 1;
    int j0 = blockIdx.x << 7;
    int w0 = blockIdx.y << 6;
    f32x4 acc[4][2];
#pragma unroll
    for (int m = 0; m < 4; m++)
#pragma unroll
        for (int n = 0; n < 2; n++) acc[m][n] = (f32x4)0.f;

    int l15 = lane & 15;
    int lhi = lane >> 4;
    int rsw = l15 & 7;  // row&7 for all fragment rows this lane touches
    for (int kk = 0; kk < 1536; kk += 64) {
        int ca = (kk < 1024) ? kk : (kk - 1024);  // h col: hi,lo,hi
        int cb = (kk < 512) ? kk : (kk - 512);    // a col: hi,hi,lo
#pragma unroll
        for (int it = 0; it < 4; it++) {
            int slot = it * 256 + t;
            int r = slot >> 3, sl = slot & 7;
            gload16(H + (j0 + r) * 1024 + ca + ((sl ^ (r & 7)) << 3),
                    At + slot * 8);
        }
#pragma unroll
        for (int it = 0; it < 2; it++) {
            int slot = it * 256 + t;
            int r = slot >> 3, sl = slot & 7;
            gload16(AT + (w0 + r) * 1024 + cb + ((sl ^ (r & 7)) << 3),
                    Bt + slot * 8);
        }
        __syncthreads();
#pragma unroll
        for (int kh = 0; kh < 2; kh++) {
            int soff = ((kh * 4 + lhi) ^ rsw) << 3;
            short8 a[4], b[2];
#pragma unroll
            for (int m = 0; m < 4; m++)
                a[m] = *(const short8*)&At[(wm * 64 + m * 16 + l15) * 64 + soff];
#pragma unroll
            for (int n = 0; n < 2; n++)
                b[n] = *(const short8*)&Bt[(wn * 32 + n * 16 + l15) * 64 + soff];
#pragma unroll
            for (int m = 0; m < 4; m++)
#pragma unroll
                for (int n = 0; n < 2; n++)
                    acc[m][n] = __builtin_amdgcn_mfma_f32_16x16x32_bf16(
                        a[m], b[n], acc[m][n], 0, 0, 0);
        }
        __syncthreads();
    }
    // C/D: col = lane&15, row = (lane>>4)*4 + reg
#pragma unroll
    for (int m = 0; m < 4; m++) {
#pragma unroll
        for (int n = 0; n < 2; n++) {
#pragma unroll
            for (int r = 0; r < 4; r++) {
                int row = j0 + wm * 64 + m * 16 + lhi * 4 + r;
                int col = w0 + wn * 32 + n * 16 + l15;
                int ih = row * 1024 + col;
                float bf = b2f(base[ih]) + b2f(base[ih + 512]);
                float f = 0.05f * bf + 0.95f * acc[m][n][r];
                unsigned short hi = f2b(f);
                dst[ih] = hi;
                dst[ih + 512] = f2b(f - b2f(hi));
            }
        }
    }
}

// dst[n][o][l][v] (+)= b[o] + sum_c h0*W[o,c] + h1*W[o,c+32] + h2*W[o,c+64]
template <int ACCUM>
__global__ __launch_bounds__(256) void chanmix_kernel(
    const unsigned int* __restrict__ h0, const unsigned int* __restrict__ h1,
    const unsigned int* __restrict__ h2, const float* __restrict__ w,
    const float* __restrict__ b, unsigned int* __restrict__ dst_u) {
    __shared__ float ws[32 * 96];
    int bid = blockIdx.x;
    int vc = bid & 3, l = (bid >> 2) & 63, n = bid >> 8;
    int t = threadIdx.x;
    int vl = t & 63, q = t >> 6;
    for (int i = t; i < 32 * 96; i += 256) ws[i] = w[i];
    __syncthreads();
    float acc[8][2];
#pragma unroll
    for (int oo = 0; oo < 8; oo++) {
        float bb = b[q * 8 + oo];
        acc[oo][0] = bb;
        acc[oo][1] = bb;
    }
    int uoff = vc * 64 + vl;
    for (int c = 0; c < 32; c++) {
        int j = (n * 32 + c) * 64 + l;
        unsigned int h0h = h0[j * 512 + uoff], h0l = h0[j * 512 + 256 + uoff];
        unsigned int h1h = h1[j * 512 + uoff], h1l = h1[j * 512 + 256 + uoff];
        unsigned int h2h = h2[j * 512 + uoff], h2l = h2[j * 512 + 256 + uoff];
        float x0l = ulo(h0h) + ulo(h0l), x0h = uhi(h0h) + uhi(h0l);
        float x1l = ulo(h1h) + ulo(h1l), x1h = uhi(h1h) + uhi(h1l);
        float x2l = ulo(h2h) + ulo(h2l), x2h = uhi(h2h) + uhi(h2l);
#pragma unroll
        for (int oo = 0; oo < 8; oo++) {
            int o = q * 8 + oo;
            float w0c = ws[o * 96 + c];
            float w1c = ws[o * 96 + 32 + c];
            float w2c = ws[o * 96 + 64 + c];
            acc[oo][0] += x0l * w0c + x1l * w1c + x2l * w2c;
            acc[oo][1] += x0h * w0c + x1h * w1c + x2h * w2c;
        }
    }
#pragma unroll
    for (int oo = 0; oo < 8; oo++) {
        int o = q * 8 + oo;
        int j = (n * 32 + o) * 64 + l;
        float a0 = acc[oo][0], a1 = acc[oo][1];
        if (ACCUM) {
            unsigned int oh = dst_u[j * 512 + uoff];
            unsigned int ol = dst_u[j * 512 + 256 + uoff];
            a0 += ulo(oh) + ulo(ol);
            a1 += uhi(oh) + uhi(ol);
        }
        unsigned short hi0 = f2b(a0), hi1 = f2b(a1);
        float lo0 = a0 - b2f(hi0), lo1 = a1 - b2f(hi1);
        dst_u[j * 512 + uoff] = (unsigned int)hi0 | ((unsigned int)hi1 << 16);
        dst_u[j * 512 + 256 + uoff] = pk2(lo0, lo1);
    }
}

// LayerNorm#1 (over l) + transpose to v-major: ht[(n*512+v)][c*64+l] packed
// uint32 (hi | lo<<16). grid = n(4) x c(32) x vb(8) = 1024 blocks, 256 thr.
__global__ __launch_bounds__(256) void lnt_kernel(
    const unsigned short* __restrict__ h, const float* __restrict__ lw,
    const float* __restrict__ lb, unsigned int* __restrict__ ht) {
    __shared__ float th[64][65];        // [l][v] f32
    __shared__ unsigned int tt[64][65]; // [v][l] packed
    __shared__ float p1s[4][64], p2s[4][64], ms[64], is[64];
    int b = blockIdx.x;
    int c = b & 31, vb = (b >> 5) & 7, n = b >> 8;
    int t = threadIdx.x;
    // load 64 l x 64 v (hi+lo) -> f32 tile
#pragma unroll
    for (int half = 0; half < 2; half++) {
        int s = half * 256 + t;
        int l = s >> 3, q = s & 7;
        const unsigned short* p =
            h + (size_t)((n * 32 + c) * 64 + l) * 1024 + vb * 64 + q * 8;
        short8 hiv = *(const short8*)p;
        short8 lov = *(const short8*)(p + 512);
#pragma unroll
        for (int i = 0; i < 8; i++)
            th[l][q * 8 + i] =
                b2f((unsigned short)hiv[i]) + b2f((unsigned short)lov[i]);
    }
    __syncthreads();
    {
        int v = t & 63, g = t >> 6;
        float s = 0.f, sq = 0.f;
#pragma unroll
        for (int i = 0; i < 16; i++) {
            float f = th[g * 16 + i][v];
            s += f;
            sq += f * f;
        }
        p1s[g][v] = s;
        p2s[g][v] = sq;
    }
    __syncthreads();
    if (t < 64) {
        float s = p1s[0][t] + p1s[1][t] + p1s[2][t] + p1s[3][t];
        float sq = p2s[0][t] + p2s[1][t] + p2s[2][t] + p2s[3][t];
        float m = s * (1.f / 64.f);
        float var = fmaxf(sq * (1.f / 64.f) - m * m, 0.f);
        ms[t] = m;
        is[t] = 1.f / sqrtf(var + 1e-12f);
    }
    __syncthreads();
    {
        int v = t & 63, g = t >> 6;
        float m = ms[v], inv = is[v];
#pragma unroll
        for (int i = 0; i < 16; i++) {
            int l = g * 16 + i;
            float f = lw[l] * (th[l][v] - m) * inv + lb[l];
            unsigned short hi = f2b(f);
            tt[v][l] = (unsigned int)hi | ((unsigned int)f2b(f - b2f(hi)) << 16);
        }
    }
    __syncthreads();
    {
        int vr = t >> 2, ch = t & 3;
        unsigned int* dstp =
            ht + (size_t)(n * 512 + vb * 64 + vr) * 2048 + c * 64 + ch * 16;
#pragma unroll
        for (int i = 0; i < 4; i++) {
            uint4 val;
            val.x = tt[vr][ch * 16 + i * 4 + 0];
            val.y = tt[vr][ch * 16 + i * 4 + 1];
            val.z = tt[vr][ch * 16 + i * 4 + 2];
            val.w = tt[vr][ch * 16 + i * 4 + 3];
            *(uint4*)(dstp + i * 4) = val;
        }
    }
}

// fused end1+selu+end2+LN#2+sum-over-o2. One wave per (n,v); 512 blocks x 256.
__global__ __launch_bounds__(256) void end_fused(
    const unsigned int* __restrict__ ht, const float* __restrict__ w1,
    const float* __restrict__ b1, const float* __restrict__ w2,
    const float* __restrict__ b2, const float* __restrict__ lw,
    const float* __restrict__ lb, float* __restrict__ out) {
    __shared__ float w1s[64 * 32];  // 8 KB
    __shared__ float w2s[64 * 64];  // 16 KB
    __shared__ float b1s[64], b2s[64], lws[64], lbs[64];
    int t = threadIdx.x;
    for (int i = t; i < 2048; i += 256) w1s[i] = w1[i];
    for (int i = t; i < 4096; i += 256) w2s[i] = w2[i];
    if (t < 64) {
        b1s[t] = b1[t];
        b2s[t] = b2[t];
        lws[t] = lw[t];
        lbs[t] = lb[t];
    }
    __syncthreads();
    int wid = t >> 6, lane = t & 63;
    int gw = blockIdx.x * 4 + wid;
    int v = gw & 511, n = gw >> 9;
    const unsigned int* row = ht + (size_t)(n * 512 + v) * 2048;
    float hv[32];
#pragma unroll
    for (int c = 0; c < 32; c++) {
        unsigned int u = row[c * 64 + lane];
        hv[c] = ulo(u) + uhi(u);
    }
    float e1[64];
#pragma unroll
    for (int o1 = 0; o1 < 64; o1++) {
        float a = b1s[o1];
#pragma unroll
        for (int c = 0; c < 32; c++) a += w1s[o1 * 32 + c] * hv[c];
        e1[o1] = selu_f(a);
    }
    float lwl = lws[lane], lbl = lbs[lane];
    float accout = 0.f;
    for (int o2 = 0; o2 < 64; o2++) {
        float e2 = b2s[o2];
#pragma unroll
        for (int o1 = 0; o1 < 64; o1++) e2 += w2s[o2 * 64 + o1] * e1[o1];
        float m = wred(e2) * (1.f / 64.f);
        float d = e2 - m;
        float q = wred(d * d);
        float inv = 1.f / sqrtf(q * (1.f / 64.f) + 1e-12f);
        accout += lwl * d * inv + lbl;
    }
    out[(n * 64 + lane) * 512 + v] = accout;
}

// ---------------- launch ----------------

extern "C" void kernel_launch(void* const* d_in, const int* in_sizes, int n_in,
                              void* d_out, int out_size, void* d_ws,
                              size_t ws_size, hipStream_t stream) {
    const float* x = (const float*)d_in[0];
    const float* emb1 = (const float*)d_in[1];
    const float* emb2 = (const float*)d_in[2];
    const float* lin1_w = (const float*)d_in[3];
    const float* lin1_b = (const float*)d_in[4];
    const float* lin2_w = (const float*)d_in[5];
    const float* lin2_b = (const float*)d_in[6];
    const float* start_w = (const float*)d_in[7];
    const float* start_b = (const float*)d_in[8];
    const float* g1_w = (const float*)d_in[9];
    const float* g1_b = (const float*)d_in[10];
    const float* g2_w = (const float*)d_in[11];
    const float* g2_b = (const float*)d_in[12];
    const float* ln_w = (const float*)d_in[13];
    const float* ln_b = (const float*)d_in[14];
    const float* end1_w = (const float*)d_in[15];
    const float* end1_b = (const float*)d_in[16];
    const float* end2_w = (const float*)d_in[17];
    const float* end2_b = (const float*)d_in[18];
    float* out = (float*)d_out;

    char* ws = (char*)d_ws;
    float* nv1 = (float*)(ws + 0);
    float* nv2 = (float*)(ws + 131072);
    float* adp = (float*)(ws + 262144);                     // 1 MB f32
    unsigned short* a1T = (unsigned short*)(ws + 1310720);  // 1 MB hi/lo
    unsigned short* a2T = (unsigned short*)(ws + 2359296);  // 1 MB hi/lo
    float* rowsump = (float*)(ws + 3407872);
    float* colsum = (float*)(ws + 3409920);
    unsigned short* hA = (unsigned short*)(ws + 4194304);   // 16 MB split
    unsigned short* hB = (unsigned short*)(ws + 20971520);  // 16 MB
    unsigned short* p1 = (unsigned short*)(ws + 37748736);  // 16 MB
    unsigned short* p2 = (unsigned short*)(ws + 54525952);  // 16 MB

    nodevec_kernel<<<512, 64, 0, stream>>>(emb1, lin1_w, lin1_b, nv1);
    nodevec_kernel<<<512, 64, 0, stream>>>(emb2, lin2_w, lin2_b, nv2);
    adjacency_kernel<<<512, 512, 0, stream>>>(nv1, nv2, adp);
    topk_kernel<<<512, 256, 0, stream>>>(adp, rowsump);
    colsum_kernel<<<2, 256, 0, stream>>>(adp, colsum);
    normalize_kernel<<<512, 256, 0, stream>>>(adp, rowsump, colsum, a1T, a2T);

    start_kernel<<<256, 256, 0, stream>>>(x, start_w, start_b, (unsigned int*)hA);

    dim3 pgrid(64, 8);
    unsigned short* cur = hA;
    unsigned short* nxt = hB;
    for (int layer = 0; layer < 2; layer++) {
        const float* w1 = g1_w + layer * 32 * 96;
        const float* bb1 = g1_b + layer * 32;
        const float* w2 = g2_w + layer * 32 * 96;
        const float* bb2 = g2_b + layer * 32;
        prop_mfma<<<pgrid, 256, 0, stream>>>(cur, cur, a1T, p1);
        prop_mfma<<<pgrid, 256, 0, stream>>>(p1, cur, a1T, p2);
        chanmix_kernel<0><<<1024, 256, 0, stream>>>(
            (const unsigned int*)cur, (const unsigned int*)p1,
            (const unsigned int*)p2, w1, bb1, (unsigned int*)nxt);
        prop_mfma<<<pgrid, 256, 0, stream>>>(cur, cur, a2T, p1);
        prop_mfma<<<pgrid, 256, 0, stream>>>(p1, cur, a2T, p2);
        chanmix_kernel<1><<<1024, 256, 0, stream>>>(
            (const unsigned int*)cur, (const unsigned int*)p1,
            (const unsigned int*)p2, w2, bb2, (unsigned int*)nxt);
        unsigned short* tmp = cur;
        cur = nxt;
        nxt = tmp;
    }

    // LN#1 + transpose into p1 (free by now), then fused end stage
    lnt_kernel<<<1024, 256, 0, stream>>>(cur, ln_w, ln_b, (unsigned int*)p1);
    end_fused<<<512, 256, 0, stream>>>((const unsigned int*)p1, end1_w, end1_b,
                                       end2_w, end2_b, ln_w, ln_b, out);
}